// Round 1
// baseline (1480.171 us; speedup 1.0000x reference)
//
#include <hip/hip_runtime.h>
#include <hip/hip_bf16.h>

// GraphSAGE: 4x SAGEConv(mean) + MLP1(8192->256->1 over flat view) + BN(B=8) + MLP2
// N=65536 nodes, E=524288 edges, H=256, IN=128, out=[8,8]=64 floats.
//
// ws layout (floats unless noted):
//   BUF0 : 16,777,216   (64 MB)  [N,256] row-stride 256
//   BUF1 : 16,777,216   (64 MB)
//   T1   : 524,288      (2 MB)   [2048,256]
//   pooled: 2048
//   inv_cnt: 65536
//   ideg  : 65536 (int)
//   row_ptr: 65544 (int, padded)
//   cursor : 65536 (int)
//   csr_src: 524288 (int)
// total ~140 MB

#define NN 65536
#define EE 524288

__global__ void gs_zero_deg(int* deg) {
    int i = blockIdx.x * 256 + threadIdx.x;
    if (i < NN) deg[i] = 0;
}

__global__ void gs_concat(const float* __restrict__ x, const float* __restrict__ g0,
                          const float* __restrict__ g1, const float* __restrict__ g2,
                          float* __restrict__ h) {
    int idx = blockIdx.x * 256 + threadIdx.x;   // N*128 total
    int n = idx >> 7, c = idx & 127;
    float v;
    if (c < 32)       v = x[n * 32 + c];
    else if (c < 64)  v = g0[n * 32 + (c - 32)];
    else if (c < 96)  v = g1[n * 32 + (c - 64)];
    else              v = g2[n * 32 + (c - 96)];
    h[(size_t)n * 256 + c] = v;
}

__global__ void gs_hist(const int* __restrict__ dst, int* __restrict__ deg) {
    int e = blockIdx.x * 256 + threadIdx.x;
    atomicAdd(&deg[dst[e]], 1);
}

// single block, 1024 threads, exclusive scan of deg[65536] -> row_ptr, cursor, inv_cnt
__global__ void gs_scan(const int* __restrict__ deg, int* __restrict__ row_ptr,
                        int* __restrict__ cursor, float* __restrict__ inv_cnt) {
    __shared__ int part[1024];
    int t = threadIdx.x;
    int base = t * 64;
    int s = 0;
    for (int i = 0; i < 64; ++i) s += deg[base + i];
    part[t] = s;
    __syncthreads();
    for (int off = 1; off < 1024; off <<= 1) {
        int add = (t >= off) ? part[t - off] : 0;
        __syncthreads();
        part[t] += add;
        __syncthreads();
    }
    int run = (t == 0) ? 0 : part[t - 1];
    for (int i = 0; i < 64; ++i) {
        int n = base + i;
        int d = deg[n];
        row_ptr[n] = run;
        cursor[n]  = run;
        inv_cnt[n] = 1.0f / (float)(d > 0 ? d : 1);
        run += d;
    }
    if (t == 1023) row_ptr[NN] = run;
}

__global__ void gs_bucket(const int* __restrict__ src, const int* __restrict__ dst,
                          int* __restrict__ cursor, int* __restrict__ csr_src) {
    int e = blockIdx.x * 256 + threadIdx.x;
    int d = dst[e];
    int p = atomicAdd(&cursor[d], 1);
    csr_src[p] = src[e];
}

// one wave per node; DIM=128 -> float2/lane, DIM=256 -> float4/lane; row stride always 256
template <int DIM>
__global__ void gs_agg(const float* __restrict__ h, const int* __restrict__ row_ptr,
                       const int* __restrict__ csr_src, const float* __restrict__ inv_cnt,
                       float* __restrict__ agg) {
    int wave = threadIdx.x >> 6;
    int lane = threadIdx.x & 63;
    int n = blockIdx.x * 4 + wave;
    int beg = row_ptr[n], end = row_ptr[n + 1];
    float iv = inv_cnt[n];
    if constexpr (DIM == 256) {
        int col = lane * 4;
        float4 acc = {0.f, 0.f, 0.f, 0.f};
        for (int e = beg; e < end; ++e) {
            int s = csr_src[e];
            float4 v = *(const float4*)&h[(size_t)s * 256 + col];
            acc.x += v.x; acc.y += v.y; acc.z += v.z; acc.w += v.w;
        }
        acc.x *= iv; acc.y *= iv; acc.z *= iv; acc.w *= iv;
        *(float4*)&agg[(size_t)n * 256 + col] = acc;
    } else {
        int col = lane * 2;
        float2 acc = {0.f, 0.f};
        for (int e = beg; e < end; ++e) {
            int s = csr_src[e];
            float2 v = *(const float2*)&h[(size_t)s * 256 + col];
            acc.x += v.x; acc.y += v.y;
        }
        acc.x *= iv; acc.y *= iv;
        *(float2*)&agg[(size_t)n * 256 + col] = acc;
    }
}

// C[M,256] = relu(A1@W1 + A2@W2 + bias). A row stride 256. Tile 64x256, 256 thr, 4x16/thr.
// C may alias A1 (each block owns its full 64-row slice; stores only in epilogue).
template <int K>
__global__ void gs_layer_gemm(const float* A1, const float* __restrict__ W1,
                              const float* __restrict__ A2, const float* __restrict__ W2,
                              const float* __restrict__ bias, float* C) {
    __shared__ float As[16][64];
    __shared__ float Bs[16][256];
    const int t = threadIdx.x;
    const int tx = t & 15;
    const int ty = t >> 4;
    const size_t row0 = (size_t)blockIdx.x * 64;
    float acc[4][16] = {};
    for (int phase = 0; phase < 2; ++phase) {
        const float* A = phase ? A2 : A1;
        const float* W = phase ? W2 : W1;
        for (int kc = 0; kc < K; kc += 16) {
            {
                int r = t >> 2, q = t & 3;
                const float4 v = *(const float4*)&A[(row0 + r) * 256 + kc + q * 4];
                As[q * 4 + 0][r] = v.x; As[q * 4 + 1][r] = v.y;
                As[q * 4 + 2][r] = v.z; As[q * 4 + 3][r] = v.w;
            }
#pragma unroll
            for (int l = 0; l < 4; ++l) {
                int fi = l * 256 + t;
                int kk = fi >> 6, c4 = fi & 63;
                *(float4*)&Bs[kk][c4 * 4] = *(const float4*)&W[(size_t)(kc + kk) * 256 + c4 * 4];
            }
            __syncthreads();
#pragma unroll
            for (int k = 0; k < 16; ++k) {
                const float4 a = *(const float4*)&As[k][ty * 4];
                const float av[4] = {a.x, a.y, a.z, a.w};
#pragma unroll
                for (int j = 0; j < 4; ++j) {
                    const float4 b = *(const float4*)&Bs[k][j * 64 + tx * 4];
#pragma unroll
                    for (int i = 0; i < 4; ++i) {
                        acc[i][j * 4 + 0] = fmaf(av[i], b.x, acc[i][j * 4 + 0]);
                        acc[i][j * 4 + 1] = fmaf(av[i], b.y, acc[i][j * 4 + 1]);
                        acc[i][j * 4 + 2] = fmaf(av[i], b.z, acc[i][j * 4 + 2]);
                        acc[i][j * 4 + 3] = fmaf(av[i], b.w, acc[i][j * 4 + 3]);
                    }
                }
            }
            __syncthreads();
        }
    }
#pragma unroll
    for (int j = 0; j < 4; ++j) {
        int col = j * 64 + tx * 4;
        const float4 bv = *(const float4*)&bias[col];
#pragma unroll
        for (int i = 0; i < 4; ++i) {
            size_t row = row0 + ty * 4 + i;
            float4 o;
            o.x = fmaxf(acc[i][j * 4 + 0] + bv.x, 0.f);
            o.y = fmaxf(acc[i][j * 4 + 1] + bv.y, 0.f);
            o.z = fmaxf(acc[i][j * 4 + 2] + bv.z, 0.f);
            o.w = fmaxf(acc[i][j * 4 + 3] + bv.w, 0.f);
            *(float4*)&C[row * 256 + col] = o;
        }
    }
}

// MLP1 split-K GEMM: A[2048,8192] @ W[8192,256]; grid (32 row-tiles, 16 k-slices of 512)
__global__ void gs_mlp1_gemm(const float* __restrict__ A, const float* __restrict__ W,
                             float* __restrict__ part) {
    __shared__ float As[16][64];
    __shared__ float Bs[16][256];
    const int t = threadIdx.x;
    const int tx = t & 15;
    const int ty = t >> 4;
    const size_t row0 = (size_t)blockIdx.x * 64;
    const int kbase = blockIdx.y * 512;
    float acc[4][16] = {};
    for (int kc = 0; kc < 512; kc += 16) {
        {
            int r = t >> 2, q = t & 3;
            const float4 v = *(const float4*)&A[(row0 + r) * 8192 + kbase + kc + q * 4];
            As[q * 4 + 0][r] = v.x; As[q * 4 + 1][r] = v.y;
            As[q * 4 + 2][r] = v.z; As[q * 4 + 3][r] = v.w;
        }
#pragma unroll
        for (int l = 0; l < 4; ++l) {
            int fi = l * 256 + t;
            int kk = fi >> 6, c4 = fi & 63;
            *(float4*)&Bs[kk][c4 * 4] =
                *(const float4*)&W[(size_t)(kbase + kc + kk) * 256 + c4 * 4];
        }
        __syncthreads();
#pragma unroll
        for (int k = 0; k < 16; ++k) {
            const float4 a = *(const float4*)&As[k][ty * 4];
            const float av[4] = {a.x, a.y, a.z, a.w};
#pragma unroll
            for (int j = 0; j < 4; ++j) {
                const float4 b = *(const float4*)&Bs[k][j * 64 + tx * 4];
#pragma unroll
                for (int i = 0; i < 4; ++i) {
                    acc[i][j * 4 + 0] = fmaf(av[i], b.x, acc[i][j * 4 + 0]);
                    acc[i][j * 4 + 1] = fmaf(av[i], b.y, acc[i][j * 4 + 1]);
                    acc[i][j * 4 + 2] = fmaf(av[i], b.z, acc[i][j * 4 + 2]);
                    acc[i][j * 4 + 3] = fmaf(av[i], b.w, acc[i][j * 4 + 3]);
                }
            }
        }
        __syncthreads();
    }
    const size_t kofs = (size_t)blockIdx.y * 2048 * 256;
#pragma unroll
    for (int j = 0; j < 4; ++j) {
        int col = j * 64 + tx * 4;
#pragma unroll
        for (int i = 0; i < 4; ++i) {
            size_t row = row0 + ty * 4 + i;
            float4 o;
            o.x = acc[i][j * 4 + 0]; o.y = acc[i][j * 4 + 1];
            o.z = acc[i][j * 4 + 2]; o.w = acc[i][j * 4 + 3];
            *(float4*)&part[kofs + row * 256 + col] = o;
        }
    }
}

__global__ void gs_mlp1_reduce(const float* __restrict__ part, const float* __restrict__ b1,
                               float* __restrict__ t1) {
    int idx = blockIdx.x * 256 + threadIdx.x;   // 2048*256
    float s = 0.f;
#pragma unroll
    for (int ks = 0; ks < 16; ++ks) s += part[(size_t)ks * 524288 + idx];
    s += b1[idx & 255];
    t1[idx] = fmaxf(s, 0.f);
}

__global__ void gs_pool(const float* __restrict__ t1, const float* __restrict__ W2,
                        const float* __restrict__ b2, float* __restrict__ pooled) {
    int r = blockIdx.x;     // 2048
    int l = threadIdx.x;    // 64
    float acc = 0.f;
#pragma unroll
    for (int q = 0; q < 4; ++q) {
        int c = l + q * 64;
        acc = fmaf(t1[(size_t)r * 256 + c], W2[c], acc);
    }
    for (int off = 32; off > 0; off >>= 1) acc += __shfl_down(acc, off);
    if (l == 0) pooled[r] = acc + b2[0];
}

__global__ void gs_bn_mlp2(const float* __restrict__ pooled, const float* __restrict__ gamma,
                           const float* __restrict__ beta, const float* __restrict__ W1,
                           const float* __restrict__ b1, const float* __restrict__ W2,
                           const float* __restrict__ b2, float* __restrict__ out) {
    __shared__ float hb[8][256];
    __shared__ float h2[8][256];
    int t = threadIdx.x;    // 256
    {
        float v[8];
        float m = 0.f;
#pragma unroll
        for (int b = 0; b < 8; ++b) { v[b] = pooled[b * 256 + t]; m += v[b]; }
        m *= 0.125f;
        float var = 0.f;
#pragma unroll
        for (int b = 0; b < 8; ++b) { float d = v[b] - m; var += d * d; }
        var *= 0.125f;
        float is = 1.0f / sqrtf(var + 1e-5f);
        float g = gamma[t], bt = beta[t];
#pragma unroll
        for (int b = 0; b < 8; ++b) hb[b][t] = fmaxf((v[b] - m) * is * g + bt, 0.f);
    }
    __syncthreads();
    {
        float acc[8] = {};
        for (int i = 0; i < 256; ++i) {
            float w = W1[i * 256 + t];
#pragma unroll
            for (int b = 0; b < 8; ++b) acc[b] = fmaf(hb[b][i], w, acc[b]);
        }
        float bb = b1[t];
#pragma unroll
        for (int b = 0; b < 8; ++b) h2[b][t] = fmaxf(acc[b] + bb, 0.f);
    }
    __syncthreads();
    if (t < 64) {
        int b = t >> 3, o = t & 7;
        float acc = 0.f;
        for (int j = 0; j < 256; ++j) acc = fmaf(h2[b][j], W2[j * 8 + o], acc);
        out[b * 8 + o] = acc + b2[o];
    }
}

extern "C" void kernel_launch(void* const* d_in, const int* in_sizes, int n_in,
                              void* d_out, int out_size, void* d_ws, size_t ws_size,
                              hipStream_t stream) {
    const float* x  = (const float*)d_in[0];
    const float* g0 = (const float*)d_in[1];
    const float* g1 = (const float*)d_in[2];
    const float* g2 = (const float*)d_in[3];
    const int* edge_src = (const int*)d_in[4];
    const int* edge_dst = (const int*)d_in[5];
    const float* Wl[4] = {(const float*)d_in[6], (const float*)d_in[9],
                          (const float*)d_in[12], (const float*)d_in[15]};
    const float* Wr[4] = {(const float*)d_in[7], (const float*)d_in[10],
                          (const float*)d_in[13], (const float*)d_in[16]};
    const float* bs[4] = {(const float*)d_in[8], (const float*)d_in[11],
                          (const float*)d_in[14], (const float*)d_in[17]};
    const float* mlp1_W1 = (const float*)d_in[18];
    const float* mlp1_b1 = (const float*)d_in[19];
    const float* mlp1_W2 = (const float*)d_in[20];
    const float* mlp1_b2 = (const float*)d_in[21];
    const float* bn_gamma = (const float*)d_in[22];
    const float* bn_beta  = (const float*)d_in[23];
    const float* mlp2_W1 = (const float*)d_in[24];
    const float* mlp2_b1 = (const float*)d_in[25];
    const float* mlp2_W2 = (const float*)d_in[26];
    const float* mlp2_b2 = (const float*)d_in[27];
    float* out = (float*)d_out;

    float* BUF0 = (float*)d_ws;
    float* BUF1 = BUF0 + (size_t)16777216;
    float* T1   = BUF1 + (size_t)16777216;
    float* pooled  = T1 + 524288;
    float* inv_cnt = pooled + 2048;
    int* ideg    = (int*)(inv_cnt + 65536);
    int* row_ptr = ideg + 65536;
    int* cursor  = row_ptr + 65544;    // padded
    int* csr_src = cursor + 65536;

    // --- graph prep ---
    gs_zero_deg<<<256, 256, 0, stream>>>(ideg);
    gs_concat<<<NN * 128 / 256, 256, 0, stream>>>(x, g0, g1, g2, BUF0);
    gs_hist<<<EE / 256, 256, 0, stream>>>(edge_dst, ideg);
    gs_scan<<<1, 1024, 0, stream>>>(ideg, row_ptr, cursor, inv_cnt);
    gs_bucket<<<EE / 256, 256, 0, stream>>>(edge_src, edge_dst, cursor, csr_src);

    // --- 4 SAGE layers (ping-pong BUF0/BUF1; gemm writes over the agg buffer) ---
    // L0: h0=BUF0 (128 cols), agg->BUF1, h1->BUF1
    gs_agg<128><<<NN / 4, 256, 0, stream>>>(BUF0, row_ptr, csr_src, inv_cnt, BUF1);
    gs_layer_gemm<128><<<NN / 64, 256, 0, stream>>>(BUF1, Wl[0], BUF0, Wr[0], bs[0], BUF1);
    // L1: h1=BUF1, agg->BUF0, h2->BUF0
    gs_agg<256><<<NN / 4, 256, 0, stream>>>(BUF1, row_ptr, csr_src, inv_cnt, BUF0);
    gs_layer_gemm<256><<<NN / 64, 256, 0, stream>>>(BUF0, Wl[1], BUF1, Wr[1], bs[1], BUF0);
    // L2: h2=BUF0, agg->BUF1, h3->BUF1
    gs_agg<256><<<NN / 4, 256, 0, stream>>>(BUF0, row_ptr, csr_src, inv_cnt, BUF1);
    gs_layer_gemm<256><<<NN / 64, 256, 0, stream>>>(BUF1, Wl[2], BUF0, Wr[2], bs[2], BUF1);
    // L3: h3=BUF1, agg->BUF0, h4->BUF0
    gs_agg<256><<<NN / 4, 256, 0, stream>>>(BUF1, row_ptr, csr_src, inv_cnt, BUF0);
    gs_layer_gemm<256><<<NN / 64, 256, 0, stream>>>(BUF0, Wl[3], BUF1, Wr[3], bs[3], BUF0);

    // --- MLP1: [2048,8192]@[8192,256], split-K=16, partials in BUF1 ---
    gs_mlp1_gemm<<<dim3(32, 16), 256, 0, stream>>>(BUF0, mlp1_W1, BUF1);
    gs_mlp1_reduce<<<2048, 256, 0, stream>>>(BUF1, mlp1_b1, T1);
    gs_pool<<<2048, 64, 0, stream>>>(T1, mlp1_W2, mlp1_b2, pooled);

    // --- BN + MLP2 -> out[8,8] ---
    gs_bn_mlp2<<<1, 256, 0, stream>>>(pooled, bn_gamma, bn_beta, mlp2_W1, mlp2_b1,
                                      mlp2_W2, mlp2_b2, out);
}

// Round 2
// 672.553 us; speedup vs baseline: 2.2008x; 2.2008x over previous
//
#include <hip/hip_runtime.h>
#include <hip/hip_bf16.h>

// GraphSAGE on MI355X — bf16/MFMA round.
// Layers: D = [agg | h] @ [Wl ; Wr] as ONE K=512 (K=256 for layer0) bf16 MFMA GEMM.
// Feature buffers: P0/P1 = [N,512] bf16 (cols 0..255 agg, 256..511 h), ping-pong.
// Weights transposed+combined on device each call: Wc[n][k] bf16 (B^T layout for MFMA).
//
// ws layout (bytes):
//   P0   @ 0         : 64 MB  bf16 [65536][512]   (H4 reuses first 32 MB; MLP1 partials next 32 MB)
//   P1   @ 64 MB     : 64 MB  bf16 [65536][512]   (T1/pooled reuse this after layer 3)
//   WC0  @ 128 MB    : 128 KB bf16 [256][256]
//   WC1..WC3         : 256 KB each bf16 [256][512]
//   W1T              : 4 MB   bf16 [256][8192]
//   inv_cnt          : 256 KB fp32
//   ideg/row_ptr/cursor : ints
//   csr_src          : 2 MB int
// total ~142 MB

#define NN 65536
#define EE 524288

using frag16 = __attribute__((ext_vector_type(8))) short;   // 8 x bf16
using f32x4  = __attribute__((ext_vector_type(4))) float;

__device__ __forceinline__ float b2f(unsigned short u) {
    union { unsigned u32; float f; } x; x.u32 = (unsigned)u << 16; return x.f;
}

__device__ __forceinline__ void gld_lds16(const void* g, void* l) {
    __builtin_amdgcn_global_load_lds(
        (const __attribute__((address_space(1))) void*)g,
        (__attribute__((address_space(3))) void*)l, 16, 0, 0);
}

// ---------------- graph prep (unchanged fp32/int) ----------------

__global__ void gs_zero_deg(int* deg) {
    int i = blockIdx.x * 256 + threadIdx.x;
    if (i < NN) deg[i] = 0;
}

__global__ void gs_hist(const int* __restrict__ dst, int* __restrict__ deg) {
    int e = blockIdx.x * 256 + threadIdx.x;
    atomicAdd(&deg[dst[e]], 1);
}

__global__ void gs_scan(const int* __restrict__ deg, int* __restrict__ row_ptr,
                        int* __restrict__ cursor, float* __restrict__ inv_cnt) {
    __shared__ int part[1024];
    int t = threadIdx.x;
    int base = t * 64;
    int s = 0;
    for (int i = 0; i < 64; ++i) s += deg[base + i];
    part[t] = s;
    __syncthreads();
    for (int off = 1; off < 1024; off <<= 1) {
        int add = (t >= off) ? part[t - off] : 0;
        __syncthreads();
        part[t] += add;
        __syncthreads();
    }
    int run = (t == 0) ? 0 : part[t - 1];
    for (int i = 0; i < 64; ++i) {
        int n = base + i;
        int d = deg[n];
        row_ptr[n] = run;
        cursor[n]  = run;
        inv_cnt[n] = 1.0f / (float)(d > 0 ? d : 1);
        run += d;
    }
    if (t == 1023) row_ptr[NN] = run;
}

__global__ void gs_bucket(const int* __restrict__ src, const int* __restrict__ dst,
                          int* __restrict__ cursor, int* __restrict__ csr_src) {
    int e = blockIdx.x * 256 + threadIdx.x;
    int d = dst[e];
    int p = atomicAdd(&cursor[d], 1);
    csr_src[p] = src[e];
}

// ---------------- weight transpose+convert: dst[n][kofs+k] = src[k][n] ----------------
// src [K,256] fp32, dst row-major [256][ldk] bf16.  grid (K/32, 8), block (32,8)
__global__ void gs_tcvt(const float* __restrict__ src, __hip_bfloat16* __restrict__ dst,
                        int ldk, int kofs) {
    __shared__ float tile[32][33];
    int kb = blockIdx.x * 32, nb = blockIdx.y * 32;
    int tx = threadIdx.x, ty = threadIdx.y;
#pragma unroll
    for (int i = 0; i < 32; i += 8)
        tile[ty + i][tx] = src[(size_t)(kb + ty + i) * 256 + nb + tx];
    __syncthreads();
#pragma unroll
    for (int i = 0; i < 32; i += 8) {
        int n = nb + ty + i, k = kb + tx;
        dst[(size_t)n * ldk + kofs + k] = __float2bfloat16(tile[tx][ty + i]);
    }
}

// ---------------- concat -> bf16 h0 at P0 cols 256..383 ----------------
__global__ void gs_concat_bf(const float* __restrict__ x, const float* __restrict__ g0,
                             const float* __restrict__ g1, const float* __restrict__ g2,
                             __hip_bfloat16* __restrict__ h) {
    int idx = blockIdx.x * 256 + threadIdx.x;   // N*128
    int n = idx >> 7, c = idx & 127;
    float v;
    if (c < 32)       v = x[n * 32 + c];
    else if (c < 64)  v = g0[n * 32 + (c - 32)];
    else if (c < 96)  v = g1[n * 32 + (c - 64)];
    else              v = g2[n * 32 + (c - 96)];
    h[(size_t)n * 512 + 256 + c] = __float2bfloat16(v);
}

// ---------------- mean aggregation, bf16 in/out, fp32 accumulate ----------------
// hsrc: node row at hsrc + n*512 (DIM cols); adst: out at adst + n*512 (DIM cols)
template <int DIM>
__global__ void gs_agg_bf(const __hip_bfloat16* __restrict__ hsrc,
                          __hip_bfloat16* __restrict__ adst,
                          const int* __restrict__ row_ptr, const int* __restrict__ csr_src,
                          const float* __restrict__ inv_cnt) {
    int wave = threadIdx.x >> 6;
    int lane = threadIdx.x & 63;
    int n = blockIdx.x * 4 + wave;
    int beg = row_ptr[n], end = row_ptr[n + 1];
    float iv = inv_cnt[n];
    if constexpr (DIM == 256) {
        int col = lane * 4;
        float a0 = 0.f, a1 = 0.f, a2 = 0.f, a3 = 0.f;
        for (int e = beg; e < end; ++e) {
            int s = csr_src[e];
            ushort4 v = *(const ushort4*)(hsrc + (size_t)s * 512 + col);
            a0 += b2f(v.x); a1 += b2f(v.y); a2 += b2f(v.z); a3 += b2f(v.w);
        }
        __hip_bfloat16 o[4] = {__float2bfloat16(a0 * iv), __float2bfloat16(a1 * iv),
                               __float2bfloat16(a2 * iv), __float2bfloat16(a3 * iv)};
        *(ushort4*)(adst + (size_t)n * 512 + col) = *(const ushort4*)o;
    } else {
        int col = lane * 2;
        float a0 = 0.f, a1 = 0.f;
        for (int e = beg; e < end; ++e) {
            int s = csr_src[e];
            ushort2 v = *(const ushort2*)(hsrc + (size_t)s * 512 + col);
            a0 += b2f(v.x); a1 += b2f(v.y);
        }
        __hip_bfloat16 o[2] = {__float2bfloat16(a0 * iv), __float2bfloat16(a1 * iv)};
        *(ushort2*)(adst + (size_t)n * 512 + col) = *(const ushort2*)o;
    }
}

// ---------------- MFMA GEMM core: 128x128 tile, BK=64, 4 waves (2x2 of 64x64) ----------------
// A [M, lda] bf16 row-major; Bt [256, ldb] bf16 row-major (= B transposed, n-major).
__device__ __forceinline__ void mfma_block(const __hip_bfloat16* A, int lda,
                                           const __hip_bfloat16* Bt, int ldb,
                                           int kbeg, int kend, size_t row0, size_t nbase,
                                           __hip_bfloat16* As, __hip_bfloat16* Bs,
                                           f32x4 acc[4][4]) {
    const int t = threadIdx.x;
    const int lane = t & 63;
    const int w = t >> 6;
    const int wr = (w >> 1) * 64;
    const int wc = (w & 1) * 64;
    const int srow = w * 32 + (lane >> 3);     // staging row (8 rows per wave-load)
    const int scol = (lane & 7) * 8;           // staging col (8 bf16 = 16 B per lane)
    for (int kc = kbeg; kc < kend; kc += 64) {
#pragma unroll
        for (int l = 0; l < 4; ++l) {
            gld_lds16(A + (row0 + srow + 8 * l) * (size_t)lda + kc + scol,
                      As + (w * 32 + 8 * l) * 64);
            gld_lds16(Bt + (nbase + srow + 8 * l) * (size_t)ldb + kc + scol,
                      Bs + (w * 32 + 8 * l) * 64);
        }
        __syncthreads();
#pragma unroll
        for (int kk = 0; kk < 64; kk += 32) {
            frag16 af[4], bf[4];
#pragma unroll
            for (int i = 0; i < 4; ++i)
                af[i] = *(const frag16*)(As + (wr + i * 16 + (lane & 15)) * 64 + kk + (lane >> 4) * 8);
#pragma unroll
            for (int j = 0; j < 4; ++j)
                bf[j] = *(const frag16*)(Bs + (wc + j * 16 + (lane & 15)) * 64 + kk + (lane >> 4) * 8);
#pragma unroll
            for (int i = 0; i < 4; ++i)
#pragma unroll
                for (int j = 0; j < 4; ++j)
                    acc[i][j] = __builtin_amdgcn_mfma_f32_16x16x32_bf16(af[i], bf[j], acc[i][j], 0, 0, 0);
        }
        __syncthreads();
    }
}

// layer GEMM: C[row*ldc + cofs + n] = bf16(relu(acc + bias[n])); grid (M/128, 2)
__global__ __launch_bounds__(256, 2)
void gs_gemm_bias_relu(const __hip_bfloat16* __restrict__ A, int lda, int K,
                       const __hip_bfloat16* __restrict__ Bt, int ldb,
                       const float* __restrict__ bias,
                       __hip_bfloat16* __restrict__ C, int ldc, int cofs) {
    __shared__ __hip_bfloat16 As[128 * 64];
    __shared__ __hip_bfloat16 Bs[128 * 64];
    f32x4 acc[4][4] = {};
    const size_t row0 = (size_t)blockIdx.x * 128;
    const size_t nbase = (size_t)blockIdx.y * 128;
    mfma_block(A, lda, Bt, ldb, 0, K, row0, nbase, As, Bs, acc);
    const int lane = threadIdx.x & 63;
    const int w = threadIdx.x >> 6;
    const int wr = (w >> 1) * 64, wc = (w & 1) * 64;
#pragma unroll
    for (int j = 0; j < 4; ++j) {
        int n = (int)nbase + wc + j * 16 + (lane & 15);
        float bv = bias[n];
#pragma unroll
        for (int i = 0; i < 4; ++i) {
#pragma unroll
            for (int r = 0; r < 4; ++r) {
                size_t row = row0 + wr + i * 16 + (lane >> 4) * 4 + r;
                C[row * (size_t)ldc + cofs + n] = __float2bfloat16(fmaxf(acc[i][j][r] + bv, 0.f));
            }
        }
    }
}

// MLP1 split-K: grid (16, 2, 16); k-slice 512; fp32 partials part[kz][2048][256]
__global__ __launch_bounds__(256, 2)
void gs_gemm_splitk(const __hip_bfloat16* __restrict__ A, int lda,
                    const __hip_bfloat16* __restrict__ Bt, int ldb,
                    float* __restrict__ part) {
    __shared__ __hip_bfloat16 As[128 * 64];
    __shared__ __hip_bfloat16 Bs[128 * 64];
    f32x4 acc[4][4] = {};
    const size_t row0 = (size_t)blockIdx.x * 128;
    const size_t nbase = (size_t)blockIdx.y * 128;
    const int kbeg = blockIdx.z * 512;
    mfma_block(A, lda, Bt, ldb, kbeg, kbeg + 512, row0, nbase, As, Bs, acc);
    const int lane = threadIdx.x & 63;
    const int w = threadIdx.x >> 6;
    const int wr = (w >> 1) * 64, wc = (w & 1) * 64;
    float* p = part + (size_t)blockIdx.z * 2048 * 256;
#pragma unroll
    for (int j = 0; j < 4; ++j) {
        int n = (int)nbase + wc + j * 16 + (lane & 15);
#pragma unroll
        for (int i = 0; i < 4; ++i) {
#pragma unroll
            for (int r = 0; r < 4; ++r) {
                size_t row = row0 + wr + i * 16 + (lane >> 4) * 4 + r;
                p[row * 256 + n] = acc[i][j][r];
            }
        }
    }
}

__global__ void gs_mlp1_reduce(const float* __restrict__ part, const float* __restrict__ b1,
                               float* __restrict__ t1) {
    int idx = blockIdx.x * 256 + threadIdx.x;   // 2048*256
    float s = 0.f;
#pragma unroll
    for (int ks = 0; ks < 16; ++ks) s += part[(size_t)ks * 524288 + idx];
    s += b1[idx & 255];
    t1[idx] = fmaxf(s, 0.f);
}

__global__ void gs_pool(const float* __restrict__ t1, const float* __restrict__ W2,
                        const float* __restrict__ b2, float* __restrict__ pooled) {
    int r = blockIdx.x;     // 2048
    int l = threadIdx.x;    // 64
    float acc = 0.f;
#pragma unroll
    for (int q = 0; q < 4; ++q) {
        int c = l + q * 64;
        acc = fmaf(t1[(size_t)r * 256 + c], W2[c], acc);
    }
    for (int off = 32; off > 0; off >>= 1) acc += __shfl_down(acc, off);
    if (l == 0) pooled[r] = acc + b2[0];
}

__global__ void gs_bn_mlp2(const float* __restrict__ pooled, const float* __restrict__ gamma,
                           const float* __restrict__ beta, const float* __restrict__ W1,
                           const float* __restrict__ b1, const float* __restrict__ W2,
                           const float* __restrict__ b2, float* __restrict__ out) {
    __shared__ float hb[8][256];
    __shared__ float h2[8][256];
    int t = threadIdx.x;    // 256
    {
        float v[8];
        float m = 0.f;
#pragma unroll
        for (int b = 0; b < 8; ++b) { v[b] = pooled[b * 256 + t]; m += v[b]; }
        m *= 0.125f;
        float var = 0.f;
#pragma unroll
        for (int b = 0; b < 8; ++b) { float d = v[b] - m; var += d * d; }
        var *= 0.125f;
        float is = 1.0f / sqrtf(var + 1e-5f);
        float g = gamma[t], bt = beta[t];
#pragma unroll
        for (int b = 0; b < 8; ++b) hb[b][t] = fmaxf((v[b] - m) * is * g + bt, 0.f);
    }
    __syncthreads();
    {
        float acc[8] = {};
        for (int i = 0; i < 256; ++i) {
            float w = W1[i * 256 + t];
#pragma unroll
            for (int b = 0; b < 8; ++b) acc[b] = fmaf(hb[b][i], w, acc[b]);
        }
        float bb = b1[t];
#pragma unroll
        for (int b = 0; b < 8; ++b) h2[b][t] = fmaxf(acc[b] + bb, 0.f);
    }
    __syncthreads();
    if (t < 64) {
        int b = t >> 3, o = t & 7;
        float acc = 0.f;
        for (int j = 0; j < 256; ++j) acc = fmaf(h2[b][j], W2[j * 8 + o], acc);
        out[b * 8 + o] = acc + b2[o];
    }
}

extern "C" void kernel_launch(void* const* d_in, const int* in_sizes, int n_in,
                              void* d_out, int out_size, void* d_ws, size_t ws_size,
                              hipStream_t stream) {
    const float* x  = (const float*)d_in[0];
    const float* g0 = (const float*)d_in[1];
    const float* g1 = (const float*)d_in[2];
    const float* g2 = (const float*)d_in[3];
    const int* edge_src = (const int*)d_in[4];
    const int* edge_dst = (const int*)d_in[5];
    const float* Wl[4] = {(const float*)d_in[6], (const float*)d_in[9],
                          (const float*)d_in[12], (const float*)d_in[15]};
    const float* Wr[4] = {(const float*)d_in[7], (const float*)d_in[10],
                          (const float*)d_in[13], (const float*)d_in[16]};
    const float* bs[4] = {(const float*)d_in[8], (const float*)d_in[11],
                          (const float*)d_in[14], (const float*)d_in[17]};
    const float* mlp1_W1 = (const float*)d_in[18];
    const float* mlp1_b1 = (const float*)d_in[19];
    const float* mlp1_W2 = (const float*)d_in[20];
    const float* mlp1_b2 = (const float*)d_in[21];
    const float* bn_gamma = (const float*)d_in[22];
    const float* bn_beta  = (const float*)d_in[23];
    const float* mlp2_W1 = (const float*)d_in[24];
    const float* mlp2_b1 = (const float*)d_in[25];
    const float* mlp2_W2 = (const float*)d_in[26];
    const float* mlp2_b2 = (const float*)d_in[27];
    float* out = (float*)d_out;

    char* ws = (char*)d_ws;
    __hip_bfloat16* P0 = (__hip_bfloat16*)ws;                       // [N][512]
    __hip_bfloat16* P1 = (__hip_bfloat16*)(ws + 67108864);          // [N][512]
    __hip_bfloat16* WC0 = (__hip_bfloat16*)(ws + 134217728);        // [256][256]
    __hip_bfloat16* WC1 = WC0 + 65536;                              // [256][512]
    __hip_bfloat16* WC2 = WC1 + 131072;
    __hip_bfloat16* WC3 = WC2 + 131072;
    __hip_bfloat16* W1T = WC3 + 131072;                             // [256][8192]
    float* inv_cnt = (float*)(W1T + 2097152);
    int* ideg    = (int*)(inv_cnt + 65536);
    int* row_ptr = ideg + 65536;
    int* cursor  = row_ptr + 65544;
    int* csr_src = cursor + 65536;
    // overlays:
    __hip_bfloat16* H4 = P0;                                        // [65536][256] bf16 = 32 MB
    float* PART = (float*)(ws + 33554432);                          // 16 x [2048][256] fp32 = 32 MB (P0 upper half)
    float* T1 = (float*)P1;                                         // [2048][256] fp32 (P1 free after L3)
    float* pooled = T1 + 524288;

    // --- graph prep + weight conversion ---
    gs_zero_deg<<<256, 256, 0, stream>>>(ideg);
    gs_hist<<<EE / 256, 256, 0, stream>>>(edge_dst, ideg);
    gs_scan<<<1, 1024, 0, stream>>>(ideg, row_ptr, cursor, inv_cnt);
    gs_bucket<<<EE / 256, 256, 0, stream>>>(edge_src, edge_dst, cursor, csr_src);

    dim3 tb(32, 8);
    gs_tcvt<<<dim3(4, 8),  tb, 0, stream>>>(Wl[0], WC0, 256, 0);
    gs_tcvt<<<dim3(4, 8),  tb, 0, stream>>>(Wr[0], WC0, 256, 128);
    gs_tcvt<<<dim3(8, 8),  tb, 0, stream>>>(Wl[1], WC1, 512, 0);
    gs_tcvt<<<dim3(8, 8),  tb, 0, stream>>>(Wr[1], WC1, 512, 256);
    gs_tcvt<<<dim3(8, 8),  tb, 0, stream>>>(Wl[2], WC2, 512, 0);
    gs_tcvt<<<dim3(8, 8),  tb, 0, stream>>>(Wr[2], WC2, 512, 256);
    gs_tcvt<<<dim3(8, 8),  tb, 0, stream>>>(Wl[3], WC3, 512, 0);
    gs_tcvt<<<dim3(8, 8),  tb, 0, stream>>>(Wr[3], WC3, 512, 256);
    gs_tcvt<<<dim3(256, 8), tb, 0, stream>>>(mlp1_W1, W1T, 8192, 0);

    gs_concat_bf<<<NN * 128 / 256, 256, 0, stream>>>(x, g0, g1, g2, P0);

    // --- 4 SAGE layers ---
    // L0: h0 in P0[256..383], agg0 -> P0[128..255]; A window = P0+128, K=256; out h1 -> P1[256..511]
    gs_agg_bf<128><<<NN / 4, 256, 0, stream>>>(P0 + 256, P0 + 128, row_ptr, csr_src, inv_cnt);
    gs_gemm_bias_relu<<<dim3(NN / 128, 2), 256, 0, stream>>>(P0 + 128, 512, 256, WC0, 256,
                                                             bs[0], P1, 512, 256);
    // L1: agg1 -> P1[0..255]; A = P1, K=512; out h2 -> P0[256..511]
    gs_agg_bf<256><<<NN / 4, 256, 0, stream>>>(P1 + 256, P1, row_ptr, csr_src, inv_cnt);
    gs_gemm_bias_relu<<<dim3(NN / 128, 2), 256, 0, stream>>>(P1, 512, 512, WC1, 512,
                                                             bs[1], P0, 512, 256);
    // L2
    gs_agg_bf<256><<<NN / 4, 256, 0, stream>>>(P0 + 256, P0, row_ptr, csr_src, inv_cnt);
    gs_gemm_bias_relu<<<dim3(NN / 128, 2), 256, 0, stream>>>(P0, 512, 512, WC2, 512,
                                                             bs[2], P1, 512, 256);
    // L3: out h4 -> H4 contiguous [N,256] (overwrites P0 lower half; P0 not read here)
    gs_agg_bf<256><<<NN / 4, 256, 0, stream>>>(P1 + 256, P1, row_ptr, csr_src, inv_cnt);
    gs_gemm_bias_relu<<<dim3(NN / 128, 2), 256, 0, stream>>>(P1, 512, 512, WC3, 512,
                                                             bs[3], H4, 256, 0);

    // --- MLP1: [2048,8192] @ [8192,256] bf16 split-K=16 -> fp32 partials ---
    gs_gemm_splitk<<<dim3(16, 2, 16), 256, 0, stream>>>(H4, 8192, W1T, 8192, PART);
    gs_mlp1_reduce<<<2048, 256, 0, stream>>>(PART, mlp1_b1, T1);
    gs_pool<<<2048, 64, 0, stream>>>(T1, mlp1_W2, mlp1_b2, pooled);

    // --- BN + MLP2 -> out[8,8] ---
    gs_bn_mlp2<<<1, 256, 0, stream>>>(pooled, bn_gamma, bn_beta, mlp2_W1, mlp2_b1,
                                      mlp2_W2, mlp2_b2, out);
}

// Round 4
// 557.830 us; speedup vs baseline: 2.6534x; 1.2057x over previous
//
#include <hip/hip_runtime.h>
#include <hip/hip_bf16.h>

// GraphSAGE on MI355X — bf16/MFMA + MLP-optimized gather round (R3 layout fix).
// Layers: D = [agg | h] @ [Wl ; Wr] as ONE K=512 (K=256 for layer0) bf16 MFMA GEMM.
// Feature buffers: P0/P1 = [N+1,512] bf16 (cols 0..255 agg, 256..511 h), ping-pong.
// Row N is an all-zero pad row; CSR segments are padded to a multiple of 4 edges
// pointing at row N so the gather loop runs 4 independent loads per iteration.
//
// ws layout: P0, P1 (64 MB + 1 KB each), WC0..WC3, W1T, inv_cnt, ints, padded CSR.
// Overlays after layer 3:
//   H4   = P0[0..32MB)          [2048x8192] bf16
//   T1   = P1[0..2MB)           [2048x256] fp32
//   pooled = P1+2MB             2048 fp32
//   PART = P1+4MB..P1+36MB      16 x [2048x256] fp32   <-- disjoint from T1/pooled/H4
// (R3 bug: PART at ws+34MB overran P0 into P1 base = T1 -> race -> tripwire.)

#define NN 65536
#define EE 524288
#define ROWS 65537            // N + zero pad row
#define PCSR_CAP 720896       // E + 3*N upper bound

using frag16 = __attribute__((ext_vector_type(8))) short;   // 8 x bf16
using f32x4  = __attribute__((ext_vector_type(4))) float;

__device__ __forceinline__ float b2f(unsigned short u) {
    union { unsigned u32; float f; } x; x.u32 = (unsigned)u << 16; return x.f;
}

__device__ __forceinline__ void gld_lds16(const void* g, void* l) {
    __builtin_amdgcn_global_load_lds(
        (const __attribute__((address_space(1))) void*)g,
        (__attribute__((address_space(3))) void*)l, 16, 0, 0);
}

// ---------------- graph prep ----------------

__global__ void gs_zero_deg(int* deg) {
    int i = blockIdx.x * 256 + threadIdx.x;
    if (i < NN) deg[i] = 0;
}

// zero the pad row (row NN) of both feature buffers
__global__ void gs_zero_pad(__hip_bfloat16* P0, __hip_bfloat16* P1) {
    int i = blockIdx.x * 256 + threadIdx.x;   // 512 total
    P0[(size_t)NN * 512 + i] = __float2bfloat16(0.f);
    P1[(size_t)NN * 512 + i] = __float2bfloat16(0.f);
}

__global__ void gs_hist(const int* __restrict__ dst, int* __restrict__ deg) {
    int e = blockIdx.x * 256 + threadIdx.x;
    atomicAdd(&deg[dst[e]], 1);
}

// fill padded CSR with the zero-row index
__global__ void gs_fill(int* __restrict__ pcsr) {
    int i = blockIdx.x * 256 + threadIdx.x;
    if (i < PCSR_CAP) pcsr[i] = NN;
}

// single block, 1024 threads: padded exclusive scan (pdeg = ceil4(deg)) -> prow, cursor, inv_cnt
__global__ void gs_scan(const int* __restrict__ deg, int* __restrict__ prow,
                        int* __restrict__ cursor, float* __restrict__ inv_cnt) {
    __shared__ int part[1024];
    int t = threadIdx.x;
    int base = t * 64;
    int s = 0;
    for (int i = 0; i < 64; ++i) s += (deg[base + i] + 3) & ~3;
    part[t] = s;
    __syncthreads();
    for (int off = 1; off < 1024; off <<= 1) {
        int add = (t >= off) ? part[t - off] : 0;
        __syncthreads();
        part[t] += add;
        __syncthreads();
    }
    int run = (t == 0) ? 0 : part[t - 1];
    for (int i = 0; i < 64; ++i) {
        int n = base + i;
        int d = deg[n];
        prow[n] = run;
        cursor[n] = run;
        inv_cnt[n] = 1.0f / (float)(d > 0 ? d : 1);
        run += (d + 3) & ~3;
    }
    if (t == 1023) prow[NN] = run;
}

__global__ void gs_bucket(const int* __restrict__ src, const int* __restrict__ dst,
                          int* __restrict__ cursor, int* __restrict__ pcsr) {
    int e = blockIdx.x * 256 + threadIdx.x;
    int d = dst[e];
    int p = atomicAdd(&cursor[d], 1);
    pcsr[p] = src[e];
}

// ---------------- fused weight transpose+convert (8 weight mats in one launch) ----------
// dst[n][kofs+k] = bf16(src[k][n]); grid (8, 8, 8) block (32,8); z selects matrix.
struct TcvtArgs {
    const float* src[8];
    __hip_bfloat16* dst[8];
    int ldk[8];
    int kofs[8];
    int kblk[8];   // K/32
};

__global__ void gs_tcvt_all(TcvtArgs a) {
    int z = blockIdx.z;
    if ((int)blockIdx.x >= a.kblk[z]) return;
    const float* src = a.src[z];
    __hip_bfloat16* dst = a.dst[z];
    int ldk = a.ldk[z], kofs = a.kofs[z];
    __shared__ float tile[32][33];
    int kb = blockIdx.x * 32, nb = blockIdx.y * 32;
    int tx = threadIdx.x, ty = threadIdx.y;
#pragma unroll
    for (int i = 0; i < 32; i += 8)
        tile[ty + i][tx] = src[(size_t)(kb + ty + i) * 256 + nb + tx];
    __syncthreads();
#pragma unroll
    for (int i = 0; i < 32; i += 8) {
        int n = nb + ty + i, k = kb + tx;
        dst[(size_t)n * ldk + kofs + k] = __float2bfloat16(tile[tx][ty + i]);
    }
}

// single-matrix variant for mlp1_W1 [8192,256]
__global__ void gs_tcvt(const float* __restrict__ src, __hip_bfloat16* __restrict__ dst,
                        int ldk, int kofs) {
    __shared__ float tile[32][33];
    int kb = blockIdx.x * 32, nb = blockIdx.y * 32;
    int tx = threadIdx.x, ty = threadIdx.y;
#pragma unroll
    for (int i = 0; i < 32; i += 8)
        tile[ty + i][tx] = src[(size_t)(kb + ty + i) * 256 + nb + tx];
    __syncthreads();
#pragma unroll
    for (int i = 0; i < 32; i += 8) {
        int n = nb + ty + i, k = kb + tx;
        dst[(size_t)n * ldk + kofs + k] = __float2bfloat16(tile[tx][ty + i]);
    }
}

// ---------------- concat -> bf16 h0 at P0 cols 256..383 ----------------
__global__ void gs_concat_bf(const float* __restrict__ x, const float* __restrict__ g0,
                             const float* __restrict__ g1, const float* __restrict__ g2,
                             __hip_bfloat16* __restrict__ h) {
    int idx = blockIdx.x * 256 + threadIdx.x;   // N*128
    int n = idx >> 7, c = idx & 127;
    float v;
    if (c < 32)       v = x[n * 32 + c];
    else if (c < 64)  v = g0[n * 32 + (c - 32)];
    else if (c < 96)  v = g1[n * 32 + (c - 64)];
    else              v = g2[n * 32 + (c - 96)];
    h[(size_t)n * 512 + 256 + c] = __float2bfloat16(v);
}

// ---------------- mean aggregation: 4 edges/iter, index prefetch ----------------
// hsrc: node row at hsrc + n*512 (DIM cols); adst: out at adst + n*512 (DIM cols)
template <int DIM>
__global__ void gs_agg_bf(const __hip_bfloat16* __restrict__ hsrc,
                          __hip_bfloat16* __restrict__ adst,
                          const int* __restrict__ prow, const int* __restrict__ pcsr,
                          const float* __restrict__ inv_cnt) {
    int wave = threadIdx.x >> 6;
    int lane = threadIdx.x & 63;
    int n = blockIdx.x * 4 + wave;
    int e = prow[n], pe = prow[n + 1];
    float iv = inv_cnt[n];
    if constexpr (DIM == 256) {
        const __hip_bfloat16* base = hsrc + lane * 4;
        float a0 = 0.f, a1 = 0.f, a2 = 0.f, a3 = 0.f;
        int4 s4;
        if (e < pe) s4 = *(const int4*)(pcsr + e);
        while (e < pe) {
            int4 cur = s4;
            e += 4;
            if (e < pe) s4 = *(const int4*)(pcsr + e);
            ushort4 v0 = *(const ushort4*)(base + (size_t)cur.x * 512);
            ushort4 v1 = *(const ushort4*)(base + (size_t)cur.y * 512);
            ushort4 v2 = *(const ushort4*)(base + (size_t)cur.z * 512);
            ushort4 v3 = *(const ushort4*)(base + (size_t)cur.w * 512);
            a0 += b2f(v0.x); a1 += b2f(v0.y); a2 += b2f(v0.z); a3 += b2f(v0.w);
            a0 += b2f(v1.x); a1 += b2f(v1.y); a2 += b2f(v1.z); a3 += b2f(v1.w);
            a0 += b2f(v2.x); a1 += b2f(v2.y); a2 += b2f(v2.z); a3 += b2f(v2.w);
            a0 += b2f(v3.x); a1 += b2f(v3.y); a2 += b2f(v3.z); a3 += b2f(v3.w);
        }
        __hip_bfloat16 o[4] = {__float2bfloat16(a0 * iv), __float2bfloat16(a1 * iv),
                               __float2bfloat16(a2 * iv), __float2bfloat16(a3 * iv)};
        *(ushort4*)(adst + (size_t)n * 512 + lane * 4) = *(const ushort4*)o;
    } else {
        const __hip_bfloat16* base = hsrc + lane * 2;
        float a0 = 0.f, a1 = 0.f;
        int4 s4;
        if (e < pe) s4 = *(const int4*)(pcsr + e);
        while (e < pe) {
            int4 cur = s4;
            e += 4;
            if (e < pe) s4 = *(const int4*)(pcsr + e);
            ushort2 v0 = *(const ushort2*)(base + (size_t)cur.x * 512);
            ushort2 v1 = *(const ushort2*)(base + (size_t)cur.y * 512);
            ushort2 v2 = *(const ushort2*)(base + (size_t)cur.z * 512);
            ushort2 v3 = *(const ushort2*)(base + (size_t)cur.w * 512);
            a0 += b2f(v0.x); a1 += b2f(v0.y);
            a0 += b2f(v1.x); a1 += b2f(v1.y);
            a0 += b2f(v2.x); a1 += b2f(v2.y);
            a0 += b2f(v3.x); a1 += b2f(v3.y);
        }
        __hip_bfloat16 o[2] = {__float2bfloat16(a0 * iv), __float2bfloat16(a1 * iv)};
        *(ushort2*)(adst + (size_t)n * 512 + lane * 2) = *(const ushort2*)o;
    }
}

// ---------------- MFMA GEMM core: 128x128 tile, BK=64, 4 waves (2x2 of 64x64) ----------------
__device__ __forceinline__ void mfma_block(const __hip_bfloat16* A, int lda,
                                           const __hip_bfloat16* Bt, int ldb,
                                           int kbeg, int kend, size_t row0, size_t nbase,
                                           __hip_bfloat16* As, __hip_bfloat16* Bs,
                                           f32x4 acc[4][4]) {
    const int t = threadIdx.x;
    const int lane = t & 63;
    const int w = t >> 6;
    const int wr = (w >> 1) * 64;
    const int wc = (w & 1) * 64;
    const int srow = w * 32 + (lane >> 3);
    const int scol = (lane & 7) * 8;
    for (int kc = kbeg; kc < kend; kc += 64) {
#pragma unroll
        for (int l = 0; l < 4; ++l) {
            gld_lds16(A + (row0 + srow + 8 * l) * (size_t)lda + kc + scol,
                      As + (w * 32 + 8 * l) * 64);
            gld_lds16(Bt + (nbase + srow + 8 * l) * (size_t)ldb + kc + scol,
                      Bs + (w * 32 + 8 * l) * 64);
        }
        __syncthreads();
#pragma unroll
        for (int kk = 0; kk < 64; kk += 32) {
            frag16 af[4], bf[4];
#pragma unroll
            for (int i = 0; i < 4; ++i)
                af[i] = *(const frag16*)(As + (wr + i * 16 + (lane & 15)) * 64 + kk + (lane >> 4) * 8);
#pragma unroll
            for (int j = 0; j < 4; ++j)
                bf[j] = *(const frag16*)(Bs + (wc + j * 16 + (lane & 15)) * 64 + kk + (lane >> 4) * 8);
#pragma unroll
            for (int i = 0; i < 4; ++i)
#pragma unroll
                for (int j = 0; j < 4; ++j)
                    acc[i][j] = __builtin_amdgcn_mfma_f32_16x16x32_bf16(af[i], bf[j], acc[i][j], 0, 0, 0);
        }
        __syncthreads();
    }
}

__global__ __launch_bounds__(256, 2)
void gs_gemm_bias_relu(const __hip_bfloat16* __restrict__ A, int lda, int K,
                       const __hip_bfloat16* __restrict__ Bt, int ldb,
                       const float* __restrict__ bias,
                       __hip_bfloat16* __restrict__ C, int ldc, int cofs) {
    __shared__ __hip_bfloat16 As[128 * 64];
    __shared__ __hip_bfloat16 Bs[128 * 64];
    f32x4 acc[4][4] = {};
    const size_t row0 = (size_t)blockIdx.x * 128;
    const size_t nbase = (size_t)blockIdx.y * 128;
    mfma_block(A, lda, Bt, ldb, 0, K, row0, nbase, As, Bs, acc);
    const int lane = threadIdx.x & 63;
    const int w = threadIdx.x >> 6;
    const int wr = (w >> 1) * 64, wc = (w & 1) * 64;
#pragma unroll
    for (int j = 0; j < 4; ++j) {
        int n = (int)nbase + wc + j * 16 + (lane & 15);
        float bv = bias[n];
#pragma unroll
        for (int i = 0; i < 4; ++i) {
#pragma unroll
            for (int r = 0; r < 4; ++r) {
                size_t row = row0 + wr + i * 16 + (lane >> 4) * 4 + r;
                C[row * (size_t)ldc + cofs + n] = __float2bfloat16(fmaxf(acc[i][j][r] + bv, 0.f));
            }
        }
    }
}

__global__ __launch_bounds__(256, 2)
void gs_gemm_splitk(const __hip_bfloat16* __restrict__ A, int lda,
                    const __hip_bfloat16* __restrict__ Bt, int ldb,
                    float* __restrict__ part) {
    __shared__ __hip_bfloat16 As[128 * 64];
    __shared__ __hip_bfloat16 Bs[128 * 64];
    f32x4 acc[4][4] = {};
    const size_t row0 = (size_t)blockIdx.x * 128;
    const size_t nbase = (size_t)blockIdx.y * 128;
    const int kbeg = blockIdx.z * 512;
    mfma_block(A, lda, Bt, ldb, kbeg, kbeg + 512, row0, nbase, As, Bs, acc);
    const int lane = threadIdx.x & 63;
    const int w = threadIdx.x >> 6;
    const int wr = (w >> 1) * 64, wc = (w & 1) * 64;
    float* p = part + (size_t)blockIdx.z * 2048 * 256;
#pragma unroll
    for (int j = 0; j < 4; ++j) {
        int n = (int)nbase + wc + j * 16 + (lane & 15);
#pragma unroll
        for (int i = 0; i < 4; ++i) {
#pragma unroll
            for (int r = 0; r < 4; ++r) {
                size_t row = row0 + wr + i * 16 + (lane >> 4) * 4 + r;
                p[row * 256 + n] = acc[i][j][r];
            }
        }
    }
}

__global__ void gs_mlp1_reduce(const float* __restrict__ part, const float* __restrict__ b1,
                               float* __restrict__ t1) {
    int idx = blockIdx.x * 256 + threadIdx.x;   // 2048*256
    float s = 0.f;
#pragma unroll
    for (int ks = 0; ks < 16; ++ks) s += part[(size_t)ks * 524288 + idx];
    s += b1[idx & 255];
    t1[idx] = fmaxf(s, 0.f);
}

__global__ void gs_pool(const float* __restrict__ t1, const float* __restrict__ W2,
                        const float* __restrict__ b2, float* __restrict__ pooled) {
    int r = blockIdx.x;     // 2048
    int l = threadIdx.x;    // 64
    float acc = 0.f;
#pragma unroll
    for (int q = 0; q < 4; ++q) {
        int c = l + q * 64;
        acc = fmaf(t1[(size_t)r * 256 + c], W2[c], acc);
    }
    for (int off = 32; off > 0; off >>= 1) acc += __shfl_down(acc, off);
    if (l == 0) pooled[r] = acc + b2[0];
}

__global__ void gs_bn_mlp2(const float* __restrict__ pooled, const float* __restrict__ gamma,
                           const float* __restrict__ beta, const float* __restrict__ W1,
                           const float* __restrict__ b1, const float* __restrict__ W2,
                           const float* __restrict__ b2, float* __restrict__ out) {
    __shared__ float hb[8][256];
    __shared__ float h2[8][256];
    int t = threadIdx.x;    // 256
    {
        float v[8];
        float m = 0.f;
#pragma unroll
        for (int b = 0; b < 8; ++b) { v[b] = pooled[b * 256 + t]; m += v[b]; }
        m *= 0.125f;
        float var = 0.f;
#pragma unroll
        for (int b = 0; b < 8; ++b) { float d = v[b] - m; var += d * d; }
        var *= 0.125f;
        float is = 1.0f / sqrtf(var + 1e-5f);
        float g = gamma[t], bt = beta[t];
#pragma unroll
        for (int b = 0; b < 8; ++b) hb[b][t] = fmaxf((v[b] - m) * is * g + bt, 0.f);
    }
    __syncthreads();
    {
        float acc[8] = {};
        for (int i = 0; i < 256; ++i) {
            float w = W1[i * 256 + t];
#pragma unroll
            for (int b = 0; b < 8; ++b) acc[b] = fmaf(hb[b][i], w, acc[b]);
        }
        float bb = b1[t];
#pragma unroll
        for (int b = 0; b < 8; ++b) h2[b][t] = fmaxf(acc[b] + bb, 0.f);
    }
    __syncthreads();
    if (t < 64) {
        int b = t >> 3, o = t & 7;
        float acc = 0.f;
        for (int j = 0; j < 256; ++j) acc = fmaf(h2[b][j], W2[j * 8 + o], acc);
        out[b * 8 + o] = acc + b2[o];
    }
}

extern "C" void kernel_launch(void* const* d_in, const int* in_sizes, int n_in,
                              void* d_out, int out_size, void* d_ws, size_t ws_size,
                              hipStream_t stream) {
    const float* x  = (const float*)d_in[0];
    const float* g0 = (const float*)d_in[1];
    const float* g1 = (const float*)d_in[2];
    const float* g2 = (const float*)d_in[3];
    const int* edge_src = (const int*)d_in[4];
    const int* edge_dst = (const int*)d_in[5];
    const float* Wl[4] = {(const float*)d_in[6], (const float*)d_in[9],
                          (const float*)d_in[12], (const float*)d_in[15]};
    const float* Wr[4] = {(const float*)d_in[7], (const float*)d_in[10],
                          (const float*)d_in[13], (const float*)d_in[16]};
    const float* bs[4] = {(const float*)d_in[8], (const float*)d_in[11],
                          (const float*)d_in[14], (const float*)d_in[17]};
    const float* mlp1_W1 = (const float*)d_in[18];
    const float* mlp1_b1 = (const float*)d_in[19];
    const float* mlp1_W2 = (const float*)d_in[20];
    const float* mlp1_b2 = (const float*)d_in[21];
    const float* bn_gamma = (const float*)d_in[22];
    const float* bn_beta  = (const float*)d_in[23];
    const float* mlp2_W1 = (const float*)d_in[24];
    const float* mlp2_b1 = (const float*)d_in[25];
    const float* mlp2_W2 = (const float*)d_in[26];
    const float* mlp2_b2 = (const float*)d_in[27];
    float* out = (float*)d_out;

    char* ws = (char*)d_ws;
    __hip_bfloat16* P0 = (__hip_bfloat16*)ws;                  // [ROWS][512]
    __hip_bfloat16* P1 = P0 + (size_t)ROWS * 512;              // [ROWS][512]
    __hip_bfloat16* WC0 = P1 + (size_t)ROWS * 512;             // [256][256]
    __hip_bfloat16* WC1 = WC0 + 65536;                         // [256][512]
    __hip_bfloat16* WC2 = WC1 + 131072;
    __hip_bfloat16* WC3 = WC2 + 131072;
    __hip_bfloat16* W1T = WC3 + 131072;                        // [256][8192]
    float* inv_cnt = (float*)(W1T + 2097152);
    int* ideg = (int*)(inv_cnt + 65536);
    int* prow = ideg + 65536;                                  // 65537 (+pad)
    int* cursor = prow + 65544;
    int* pcsr = cursor + 65536;                                // PCSR_CAP
    // overlays (all inside P0/P1, mutually disjoint):
    __hip_bfloat16* H4 = P0;                                   // [2048][8192] bf16 = 32 MB
    float* T1 = (float*)P1;                                    // [2048][256] fp32 = 2 MB
    float* pooled = T1 + 524288;                               // 8 KB at P1+2MB
    float* PART = (float*)((char*)P1 + (size_t)(4 << 20));     // 32 MB at P1+4MB

    // --- graph prep ---
    gs_zero_deg<<<256, 256, 0, stream>>>(ideg);
    gs_zero_pad<<<2, 256, 0, stream>>>(P0, P1);
    gs_hist<<<EE / 256, 256, 0, stream>>>(edge_dst, ideg);
    gs_scan<<<1, 1024, 0, stream>>>(ideg, prow, cursor, inv_cnt);
    gs_fill<<<(PCSR_CAP + 255) / 256, 256, 0, stream>>>(pcsr);
    gs_bucket<<<EE / 256, 256, 0, stream>>>(edge_src, edge_dst, cursor, pcsr);

    // --- weight conversion (one fused launch + W1T) ---
    {
        TcvtArgs a;
        const float* srcs[8] = {Wl[0], Wr[0], Wl[1], Wr[1], Wl[2], Wr[2], Wl[3], Wr[3]};
        __hip_bfloat16* dsts[8] = {WC0, WC0, WC1, WC1, WC2, WC2, WC3, WC3};
        int ldks[8] = {256, 256, 512, 512, 512, 512, 512, 512};
        int kofss[8] = {0, 128, 0, 256, 0, 256, 0, 256};
        int kblks[8] = {4, 4, 8, 8, 8, 8, 8, 8};
        for (int i = 0; i < 8; ++i) {
            a.src[i] = srcs[i]; a.dst[i] = dsts[i];
            a.ldk[i] = ldks[i]; a.kofs[i] = kofss[i]; a.kblk[i] = kblks[i];
        }
        gs_tcvt_all<<<dim3(8, 8, 8), dim3(32, 8), 0, stream>>>(a);
    }
    gs_tcvt<<<dim3(256, 8), dim3(32, 8), 0, stream>>>(mlp1_W1, W1T, 8192, 0);

    gs_concat_bf<<<NN * 128 / 256, 256, 0, stream>>>(x, g0, g1, g2, P0);

    // --- 4 SAGE layers ---
    gs_agg_bf<128><<<NN / 4, 256, 0, stream>>>(P0 + 256, P0 + 128, prow, pcsr, inv_cnt);
    gs_gemm_bias_relu<<<dim3(NN / 128, 2), 256, 0, stream>>>(P0 + 128, 512, 256, WC0, 256,
                                                             bs[0], P1, 512, 256);
    gs_agg_bf<256><<<NN / 4, 256, 0, stream>>>(P1 + 256, P1, prow, pcsr, inv_cnt);
    gs_gemm_bias_relu<<<dim3(NN / 128, 2), 256, 0, stream>>>(P1, 512, 512, WC1, 512,
                                                             bs[1], P0, 512, 256);
    gs_agg_bf<256><<<NN / 4, 256, 0, stream>>>(P0 + 256, P0, prow, pcsr, inv_cnt);
    gs_gemm_bias_relu<<<dim3(NN / 128, 2), 256, 0, stream>>>(P0, 512, 512, WC2, 512,
                                                             bs[2], P1, 512, 256);
    gs_agg_bf<256><<<NN / 4, 256, 0, stream>>>(P1 + 256, P1, prow, pcsr, inv_cnt);
    gs_gemm_bias_relu<<<dim3(NN / 128, 2), 256, 0, stream>>>(P1, 512, 512, WC3, 512,
                                                             bs[3], H4, 256, 0);

    // --- MLP1: [2048,8192] @ [8192,256] bf16 split-K=16 -> fp32 partials ---
    gs_gemm_splitk<<<dim3(16, 2, 16), 256, 0, stream>>>(H4, 8192, W1T, 8192, PART);
    gs_mlp1_reduce<<<2048, 256, 0, stream>>>(PART, mlp1_b1, T1);
    gs_pool<<<2048, 64, 0, stream>>>(T1, mlp1_W2, mlp1_b2, pooled);

    // --- BN + MLP2 -> out[8,8] ---
    gs_bn_mlp2<<<1, 256, 0, stream>>>(pooled, bn_gamma, bn_beta, mlp2_W1, mlp2_b1,
                                      mlp2_W2, mlp2_b2, out);
}

// Round 5
// 516.040 us; speedup vs baseline: 2.8683x; 1.0810x over previous
//
#include <hip/hip_runtime.h>
#include <hip/hip_bf16.h>

// GraphSAGE on MI355X — bf16/MFMA + MLP gather + parallel-scan prep (R5).
// Layers: D = [agg | h] @ [Wl ; Wr] as ONE K=512 (K=256 for layer0) bf16 MFMA GEMM.
// Feature buffers: P0/P1 = [N+1,512] bf16 (cols 0..255 agg, 256..511 h), ping-pong.
// Row N is an all-zero pad row; CSR segments are padded to a multiple of 4 edges
// pointing at row N so the gather loop runs 4 independent loads per iteration.
// Scan is hierarchical (reduce -> scan256 -> apply); apply also fills the pad
// slots of each segment (replaces full-array gs_fill) and zeroes the pad rows.
//
// Overlays after layer 3:
//   H4   = P0[0..32MB)          [2048x8192] bf16
//   T1   = P1[0..2MB)           [2048x256] fp32
//   pooled = P1+2MB             2048 fp32
//   PART = P1+4MB..P1+36MB      16 x [2048x256] fp32

#define NN 65536
#define EE 524288
#define ROWS 65537            // N + zero pad row
#define PCSR_CAP 720896       // E + 3*N upper bound

using frag16 = __attribute__((ext_vector_type(8))) short;   // 8 x bf16
using f32x4  = __attribute__((ext_vector_type(4))) float;

__device__ __forceinline__ float b2f(unsigned short u) {
    union { unsigned u32; float f; } x; x.u32 = (unsigned)u << 16; return x.f;
}

__device__ __forceinline__ void gld_lds16(const void* g, void* l) {
    __builtin_amdgcn_global_load_lds(
        (const __attribute__((address_space(1))) void*)g,
        (__attribute__((address_space(3))) void*)l, 16, 0, 0);
}

// ---------------- graph prep ----------------

__global__ void gs_zero_deg(int* deg) {
    int i = blockIdx.x * 256 + threadIdx.x;
    if (i < NN) deg[i] = 0;
}

__global__ void gs_hist(const int* __restrict__ dst, int* __restrict__ deg) {
    int e = blockIdx.x * 256 + threadIdx.x;
    atomicAdd(&deg[dst[e]], 1);
}

// phase 1: per-block (256 nodes) sum of padded degrees -> bsum[256]
__global__ void gs_deg_reduce(const int* __restrict__ deg, int* __restrict__ bsum) {
    int t = threadIdx.x;
    int p = (deg[blockIdx.x * 256 + t] + 3) & ~3;
#pragma unroll
    for (int off = 32; off > 0; off >>= 1) p += __shfl_down(p, off);
    __shared__ int w4[4];
    if ((t & 63) == 0) w4[t >> 6] = p;
    __syncthreads();
    if (t == 0) bsum[blockIdx.x] = w4[0] + w4[1] + w4[2] + w4[3];
}

// phase 2: one block scans the 256 block sums -> bofs (exclusive), prow[NN]=total
__global__ void gs_scan_bsum(const int* __restrict__ bsum, int* __restrict__ bofs,
                             int* __restrict__ prow) {
    __shared__ int part[256];
    int t = threadIdx.x;
    int v = bsum[t];
    part[t] = v;
    __syncthreads();
    for (int off = 1; off < 256; off <<= 1) {
        int add = (t >= off) ? part[t - off] : 0;
        __syncthreads();
        part[t] += add;
        __syncthreads();
    }
    bofs[t] = part[t] - v;
    if (t == 255) prow[NN] = part[255];
}

// phase 3: per-block scan + apply; fill pad slots of each segment; zero pad rows
__global__ void gs_scan_apply(const int* __restrict__ deg, const int* __restrict__ bofs,
                              int* __restrict__ prow, int* __restrict__ cursor,
                              float* __restrict__ inv_cnt, int* __restrict__ pcsr,
                              __hip_bfloat16* __restrict__ P0,
                              __hip_bfloat16* __restrict__ P1) {
    __shared__ int part[256];
    int t = threadIdx.x;
    int i = blockIdx.x * 256 + t;
    int d = deg[i];
    int p = (d + 3) & ~3;
    part[t] = p;
    __syncthreads();
    for (int off = 1; off < 256; off <<= 1) {
        int add = (t >= off) ? part[t - off] : 0;
        __syncthreads();
        part[t] += add;
        __syncthreads();
    }
    int beg = bofs[blockIdx.x] + part[t] - p;
    prow[i] = beg;
    cursor[i] = beg;
    inv_cnt[i] = 1.0f / (float)(d > 0 ? d : 1);
    for (int j = d; j < p; ++j) pcsr[beg + j] = NN;
    if (blockIdx.x == 0) {
        ((unsigned*)(P0 + (size_t)NN * 512))[t] = 0u;   // 256 x 4B = 1 KB = full pad row
        ((unsigned*)(P1 + (size_t)NN * 512))[t] = 0u;
    }
}

__global__ void gs_bucket(const int* __restrict__ src, const int* __restrict__ dst,
                          int* __restrict__ cursor, int* __restrict__ pcsr) {
    int e = blockIdx.x * 256 + threadIdx.x;
    int d = dst[e];
    int p = atomicAdd(&cursor[d], 1);
    pcsr[p] = src[e];
}

// ---------------- fused weight transpose+convert (8 weight mats in one launch) ----------
struct TcvtArgs {
    const float* src[8];
    __hip_bfloat16* dst[8];
    int ldk[8];
    int kofs[8];
    int kblk[8];   // K/32
};

__global__ void gs_tcvt_all(TcvtArgs a) {
    int z = blockIdx.z;
    if ((int)blockIdx.x >= a.kblk[z]) return;
    const float* src = a.src[z];
    __hip_bfloat16* dst = a.dst[z];
    int ldk = a.ldk[z], kofs = a.kofs[z];
    __shared__ float tile[32][33];
    int kb = blockIdx.x * 32, nb = blockIdx.y * 32;
    int tx = threadIdx.x, ty = threadIdx.y;
#pragma unroll
    for (int i = 0; i < 32; i += 8)
        tile[ty + i][tx] = src[(size_t)(kb + ty + i) * 256 + nb + tx];
    __syncthreads();
#pragma unroll
    for (int i = 0; i < 32; i += 8) {
        int n = nb + ty + i, k = kb + tx;
        dst[(size_t)n * ldk + kofs + k] = __float2bfloat16(tile[tx][ty + i]);
    }
}

// single-matrix variant for mlp1_W1 [8192,256]
__global__ void gs_tcvt(const float* __restrict__ src, __hip_bfloat16* __restrict__ dst,
                        int ldk, int kofs) {
    __shared__ float tile[32][33];
    int kb = blockIdx.x * 32, nb = blockIdx.y * 32;
    int tx = threadIdx.x, ty = threadIdx.y;
#pragma unroll
    for (int i = 0; i < 32; i += 8)
        tile[ty + i][tx] = src[(size_t)(kb + ty + i) * 256 + nb + tx];
    __syncthreads();
#pragma unroll
    for (int i = 0; i < 32; i += 8) {
        int n = nb + ty + i, k = kb + tx;
        dst[(size_t)n * ldk + kofs + k] = __float2bfloat16(tile[tx][ty + i]);
    }
}

// ---------------- concat -> bf16 h0 at P0 cols 256..383 ----------------
__global__ void gs_concat_bf(const float* __restrict__ x, const float* __restrict__ g0,
                             const float* __restrict__ g1, const float* __restrict__ g2,
                             __hip_bfloat16* __restrict__ h) {
    int idx = blockIdx.x * 256 + threadIdx.x;   // N*128
    int n = idx >> 7, c = idx & 127;
    float v;
    if (c < 32)       v = x[n * 32 + c];
    else if (c < 64)  v = g0[n * 32 + (c - 32)];
    else if (c < 96)  v = g1[n * 32 + (c - 64)];
    else              v = g2[n * 32 + (c - 96)];
    h[(size_t)n * 512 + 256 + c] = __float2bfloat16(v);
}

// ---------------- mean aggregation: 4 edges/iter, index prefetch ----------------
template <int DIM>
__global__ void gs_agg_bf(const __hip_bfloat16* __restrict__ hsrc,
                          __hip_bfloat16* __restrict__ adst,
                          const int* __restrict__ prow, const int* __restrict__ pcsr,
                          const float* __restrict__ inv_cnt) {
    int wave = threadIdx.x >> 6;
    int lane = threadIdx.x & 63;
    int n = blockIdx.x * 4 + wave;
    int e = prow[n], pe = prow[n + 1];
    float iv = inv_cnt[n];
    if constexpr (DIM == 256) {
        const __hip_bfloat16* base = hsrc + lane * 4;
        float a0 = 0.f, a1 = 0.f, a2 = 0.f, a3 = 0.f;
        int4 s4;
        if (e < pe) s4 = *(const int4*)(pcsr + e);
        while (e < pe) {
            int4 cur = s4;
            e += 4;
            if (e < pe) s4 = *(const int4*)(pcsr + e);
            ushort4 v0 = *(const ushort4*)(base + (size_t)cur.x * 512);
            ushort4 v1 = *(const ushort4*)(base + (size_t)cur.y * 512);
            ushort4 v2 = *(const ushort4*)(base + (size_t)cur.z * 512);
            ushort4 v3 = *(const ushort4*)(base + (size_t)cur.w * 512);
            a0 += b2f(v0.x); a1 += b2f(v0.y); a2 += b2f(v0.z); a3 += b2f(v0.w);
            a0 += b2f(v1.x); a1 += b2f(v1.y); a2 += b2f(v1.z); a3 += b2f(v1.w);
            a0 += b2f(v2.x); a1 += b2f(v2.y); a2 += b2f(v2.z); a3 += b2f(v2.w);
            a0 += b2f(v3.x); a1 += b2f(v3.y); a2 += b2f(v3.z); a3 += b2f(v3.w);
        }
        __hip_bfloat16 o[4] = {__float2bfloat16(a0 * iv), __float2bfloat16(a1 * iv),
                               __float2bfloat16(a2 * iv), __float2bfloat16(a3 * iv)};
        *(ushort4*)(adst + (size_t)n * 512 + lane * 4) = *(const ushort4*)o;
    } else {
        const __hip_bfloat16* base = hsrc + lane * 2;
        float a0 = 0.f, a1 = 0.f;
        int4 s4;
        if (e < pe) s4 = *(const int4*)(pcsr + e);
        while (e < pe) {
            int4 cur = s4;
            e += 4;
            if (e < pe) s4 = *(const int4*)(pcsr + e);
            ushort2 v0 = *(const ushort2*)(base + (size_t)cur.x * 512);
            ushort2 v1 = *(const ushort2*)(base + (size_t)cur.y * 512);
            ushort2 v2 = *(const ushort2*)(base + (size_t)cur.z * 512);
            ushort2 v3 = *(const ushort2*)(base + (size_t)cur.w * 512);
            a0 += b2f(v0.x); a1 += b2f(v0.y);
            a0 += b2f(v1.x); a1 += b2f(v1.y);
            a0 += b2f(v2.x); a1 += b2f(v2.y);
            a0 += b2f(v3.x); a1 += b2f(v3.y);
        }
        __hip_bfloat16 o[2] = {__float2bfloat16(a0 * iv), __float2bfloat16(a1 * iv)};
        *(ushort2*)(adst + (size_t)n * 512 + lane * 2) = *(const ushort2*)o;
    }
}

// ---------------- MFMA GEMM core: 128x128 tile, BK=64, 4 waves (2x2 of 64x64) ----------------
__device__ __forceinline__ void mfma_block(const __hip_bfloat16* A, int lda,
                                           const __hip_bfloat16* Bt, int ldb,
                                           int kbeg, int kend, size_t row0, size_t nbase,
                                           __hip_bfloat16* As, __hip_bfloat16* Bs,
                                           f32x4 acc[4][4]) {
    const int t = threadIdx.x;
    const int lane = t & 63;
    const int w = t >> 6;
    const int wr = (w >> 1) * 64;
    const int wc = (w & 1) * 64;
    const int srow = w * 32 + (lane >> 3);
    const int scol = (lane & 7) * 8;
    for (int kc = kbeg; kc < kend; kc += 64) {
#pragma unroll
        for (int l = 0; l < 4; ++l) {
            gld_lds16(A + (row0 + srow + 8 * l) * (size_t)lda + kc + scol,
                      As + (w * 32 + 8 * l) * 64);
            gld_lds16(Bt + (nbase + srow + 8 * l) * (size_t)ldb + kc + scol,
                      Bs + (w * 32 + 8 * l) * 64);
        }
        __syncthreads();
#pragma unroll
        for (int kk = 0; kk < 64; kk += 32) {
            frag16 af[4], bf[4];
#pragma unroll
            for (int i = 0; i < 4; ++i)
                af[i] = *(const frag16*)(As + (wr + i * 16 + (lane & 15)) * 64 + kk + (lane >> 4) * 8);
#pragma unroll
            for (int j = 0; j < 4; ++j)
                bf[j] = *(const frag16*)(Bs + (wc + j * 16 + (lane & 15)) * 64 + kk + (lane >> 4) * 8);
#pragma unroll
            for (int i = 0; i < 4; ++i)
#pragma unroll
                for (int j = 0; j < 4; ++j)
                    acc[i][j] = __builtin_amdgcn_mfma_f32_16x16x32_bf16(af[i], bf[j], acc[i][j], 0, 0, 0);
        }
        __syncthreads();
    }
}

__global__ __launch_bounds__(256, 2)
void gs_gemm_bias_relu(const __hip_bfloat16* __restrict__ A, int lda, int K,
                       const __hip_bfloat16* __restrict__ Bt, int ldb,
                       const float* __restrict__ bias,
                       __hip_bfloat16* __restrict__ C, int ldc, int cofs) {
    __shared__ __hip_bfloat16 As[128 * 64];
    __shared__ __hip_bfloat16 Bs[128 * 64];
    f32x4 acc[4][4] = {};
    const size_t row0 = (size_t)blockIdx.x * 128;
    const size_t nbase = (size_t)blockIdx.y * 128;
    mfma_block(A, lda, Bt, ldb, 0, K, row0, nbase, As, Bs, acc);
    const int lane = threadIdx.x & 63;
    const int w = threadIdx.x >> 6;
    const int wr = (w >> 1) * 64, wc = (w & 1) * 64;
#pragma unroll
    for (int j = 0; j < 4; ++j) {
        int n = (int)nbase + wc + j * 16 + (lane & 15);
        float bv = bias[n];
#pragma unroll
        for (int i = 0; i < 4; ++i) {
#pragma unroll
            for (int r = 0; r < 4; ++r) {
                size_t row = row0 + wr + i * 16 + (lane >> 4) * 4 + r;
                C[row * (size_t)ldc + cofs + n] = __float2bfloat16(fmaxf(acc[i][j][r] + bv, 0.f));
            }
        }
    }
}

__global__ __launch_bounds__(256, 2)
void gs_gemm_splitk(const __hip_bfloat16* __restrict__ A, int lda,
                    const __hip_bfloat16* __restrict__ Bt, int ldb,
                    float* __restrict__ part) {
    __shared__ __hip_bfloat16 As[128 * 64];
    __shared__ __hip_bfloat16 Bs[128 * 64];
    f32x4 acc[4][4] = {};
    const size_t row0 = (size_t)blockIdx.x * 128;
    const size_t nbase = (size_t)blockIdx.y * 128;
    const int kbeg = blockIdx.z * 512;
    mfma_block(A, lda, Bt, ldb, kbeg, kbeg + 512, row0, nbase, As, Bs, acc);
    const int lane = threadIdx.x & 63;
    const int w = threadIdx.x >> 6;
    const int wr = (w >> 1) * 64, wc = (w & 1) * 64;
    float* p = part + (size_t)blockIdx.z * 2048 * 256;
#pragma unroll
    for (int j = 0; j < 4; ++j) {
        int n = (int)nbase + wc + j * 16 + (lane & 15);
#pragma unroll
        for (int i = 0; i < 4; ++i) {
#pragma unroll
            for (int r = 0; r < 4; ++r) {
                size_t row = row0 + wr + i * 16 + (lane >> 4) * 4 + r;
                p[row * 256 + n] = acc[i][j][r];
            }
        }
    }
}

__global__ void gs_mlp1_reduce(const float* __restrict__ part, const float* __restrict__ b1,
                               float* __restrict__ t1) {
    int idx = blockIdx.x * 256 + threadIdx.x;   // 2048*256
    float s = 0.f;
#pragma unroll
    for (int ks = 0; ks < 16; ++ks) s += part[(size_t)ks * 524288 + idx];
    s += b1[idx & 255];
    t1[idx] = fmaxf(s, 0.f);
}

__global__ void gs_pool(const float* __restrict__ t1, const float* __restrict__ W2,
                        const float* __restrict__ b2, float* __restrict__ pooled) {
    int r = blockIdx.x;     // 2048
    int l = threadIdx.x;    // 64
    float acc = 0.f;
#pragma unroll
    for (int q = 0; q < 4; ++q) {
        int c = l + q * 64;
        acc = fmaf(t1[(size_t)r * 256 + c], W2[c], acc);
    }
    for (int off = 32; off > 0; off >>= 1) acc += __shfl_down(acc, off);
    if (l == 0) pooled[r] = acc + b2[0];
}

__global__ void gs_bn_mlp2(const float* __restrict__ pooled, const float* __restrict__ gamma,
                           const float* __restrict__ beta, const float* __restrict__ W1,
                           const float* __restrict__ b1, const float* __restrict__ W2,
                           const float* __restrict__ b2, float* __restrict__ out) {
    __shared__ float hb[8][256];
    __shared__ float h2[8][256];
    int t = threadIdx.x;    // 256
    {
        float v[8];
        float m = 0.f;
#pragma unroll
        for (int b = 0; b < 8; ++b) { v[b] = pooled[b * 256 + t]; m += v[b]; }
        m *= 0.125f;
        float var = 0.f;
#pragma unroll
        for (int b = 0; b < 8; ++b) { float d = v[b] - m; var += d * d; }
        var *= 0.125f;
        float is = 1.0f / sqrtf(var + 1e-5f);
        float g = gamma[t], bt = beta[t];
#pragma unroll
        for (int b = 0; b < 8; ++b) hb[b][t] = fmaxf((v[b] - m) * is * g + bt, 0.f);
    }
    __syncthreads();
    {
        float acc[8] = {};
        for (int i = 0; i < 256; ++i) {
            float w = W1[i * 256 + t];
#pragma unroll
            for (int b = 0; b < 8; ++b) acc[b] = fmaf(hb[b][i], w, acc[b]);
        }
        float bb = b1[t];
#pragma unroll
        for (int b = 0; b < 8; ++b) h2[b][t] = fmaxf(acc[b] + bb, 0.f);
    }
    __syncthreads();
    if (t < 64) {
        int b = t >> 3, o = t & 7;
        float acc = 0.f;
        for (int j = 0; j < 256; ++j) acc = fmaf(h2[b][j], W2[j * 8 + o], acc);
        out[b * 8 + o] = acc + b2[o];
    }
}

extern "C" void kernel_launch(void* const* d_in, const int* in_sizes, int n_in,
                              void* d_out, int out_size, void* d_ws, size_t ws_size,
                              hipStream_t stream) {
    const float* x  = (const float*)d_in[0];
    const float* g0 = (const float*)d_in[1];
    const float* g1 = (const float*)d_in[2];
    const float* g2 = (const float*)d_in[3];
    const int* edge_src = (const int*)d_in[4];
    const int* edge_dst = (const int*)d_in[5];
    const float* Wl[4] = {(const float*)d_in[6], (const float*)d_in[9],
                          (const float*)d_in[12], (const float*)d_in[15]};
    const float* Wr[4] = {(const float*)d_in[7], (const float*)d_in[10],
                          (const float*)d_in[13], (const float*)d_in[16]};
    const float* bs[4] = {(const float*)d_in[8], (const float*)d_in[11],
                          (const float*)d_in[14], (const float*)d_in[17]};
    const float* mlp1_W1 = (const float*)d_in[18];
    const float* mlp1_b1 = (const float*)d_in[19];
    const float* mlp1_W2 = (const float*)d_in[20];
    const float* mlp1_b2 = (const float*)d_in[21];
    const float* bn_gamma = (const float*)d_in[22];
    const float* bn_beta  = (const float*)d_in[23];
    const float* mlp2_W1 = (const float*)d_in[24];
    const float* mlp2_b1 = (const float*)d_in[25];
    const float* mlp2_W2 = (const float*)d_in[26];
    const float* mlp2_b2 = (const float*)d_in[27];
    float* out = (float*)d_out;

    char* ws = (char*)d_ws;
    __hip_bfloat16* P0 = (__hip_bfloat16*)ws;                  // [ROWS][512]
    __hip_bfloat16* P1 = P0 + (size_t)ROWS * 512;              // [ROWS][512]
    __hip_bfloat16* WC0 = P1 + (size_t)ROWS * 512;             // [256][256]
    __hip_bfloat16* WC1 = WC0 + 65536;                         // [256][512]
    __hip_bfloat16* WC2 = WC1 + 131072;
    __hip_bfloat16* WC3 = WC2 + 131072;
    __hip_bfloat16* W1T = WC3 + 131072;                        // [256][8192]
    float* inv_cnt = (float*)(W1T + 2097152);
    int* ideg = (int*)(inv_cnt + 65536);
    int* prow = ideg + 65536;                                  // 65537 (+pad)
    int* cursor = prow + 65544;
    int* bsum = cursor + 65536;                                // 256
    int* bofs = bsum + 256;                                    // 256
    int* pcsr = bofs + 256;                                    // PCSR_CAP
    // overlays (all inside P0/P1, mutually disjoint):
    __hip_bfloat16* H4 = P0;                                   // [2048][8192] bf16 = 32 MB
    float* T1 = (float*)P1;                                    // [2048][256] fp32 = 2 MB
    float* pooled = T1 + 524288;                               // 8 KB at P1+2MB
    float* PART = (float*)((char*)P1 + (size_t)(4 << 20));     // 32 MB at P1+4MB

    // --- graph prep (hierarchical scan; apply also pad-fills pcsr + zeroes pad rows) ---
    gs_zero_deg<<<256, 256, 0, stream>>>(ideg);
    gs_hist<<<EE / 256, 256, 0, stream>>>(edge_dst, ideg);
    gs_deg_reduce<<<256, 256, 0, stream>>>(ideg, bsum);
    gs_scan_bsum<<<1, 256, 0, stream>>>(bsum, bofs, prow);
    gs_scan_apply<<<256, 256, 0, stream>>>(ideg, bofs, prow, cursor, inv_cnt, pcsr, P0, P1);
    gs_bucket<<<EE / 256, 256, 0, stream>>>(edge_src, edge_dst, cursor, pcsr);

    // --- weight conversion (one fused launch + W1T) ---
    {
        TcvtArgs a;
        const float* srcs[8] = {Wl[0], Wr[0], Wl[1], Wr[1], Wl[2], Wr[2], Wl[3], Wr[3]};
        __hip_bfloat16* dsts[8] = {WC0, WC0, WC1, WC1, WC2, WC2, WC3, WC3};
        int ldks[8] = {256, 256, 512, 512, 512, 512, 512, 512};
        int kofss[8] = {0, 128, 0, 256, 0, 256, 0, 256};
        int kblks[8] = {4, 4, 8, 8, 8, 8, 8, 8};
        for (int i = 0; i < 8; ++i) {
            a.src[i] = srcs[i]; a.dst[i] = dsts[i];
            a.ldk[i] = ldks[i]; a.kofs[i] = kofss[i]; a.kblk[i] = kblks[i];
        }
        gs_tcvt_all<<<dim3(8, 8, 8), dim3(32, 8), 0, stream>>>(a);
    }
    gs_tcvt<<<dim3(256, 8), dim3(32, 8), 0, stream>>>(mlp1_W1, W1T, 8192, 0);

    gs_concat_bf<<<NN * 128 / 256, 256, 0, stream>>>(x, g0, g1, g2, P0);

    // --- 4 SAGE layers ---
    gs_agg_bf<128><<<NN / 4, 256, 0, stream>>>(P0 + 256, P0 + 128, prow, pcsr, inv_cnt);
    gs_gemm_bias_relu<<<dim3(NN / 128, 2), 256, 0, stream>>>(P0 + 128, 512, 256, WC0, 256,
                                                             bs[0], P1, 512, 256);
    gs_agg_bf<256><<<NN / 4, 256, 0, stream>>>(P1 + 256, P1, prow, pcsr, inv_cnt);
    gs_gemm_bias_relu<<<dim3(NN / 128, 2), 256, 0, stream>>>(P1, 512, 512, WC1, 512,
                                                             bs[1], P0, 512, 256);
    gs_agg_bf<256><<<NN / 4, 256, 0, stream>>>(P0 + 256, P0, prow, pcsr, inv_cnt);
    gs_gemm_bias_relu<<<dim3(NN / 128, 2), 256, 0, stream>>>(P0, 512, 512, WC2, 512,
                                                             bs[2], P1, 512, 256);
    gs_agg_bf<256><<<NN / 4, 256, 0, stream>>>(P1 + 256, P1, prow, pcsr, inv_cnt);
    gs_gemm_bias_relu<<<dim3(NN / 128, 2), 256, 0, stream>>>(P1, 512, 512, WC3, 512,
                                                             bs[3], H4, 256, 0);

    // --- MLP1: [2048,8192] @ [8192,256] bf16 split-K=16 -> fp32 partials ---
    gs_gemm_splitk<<<dim3(16, 2, 16), 256, 0, stream>>>(H4, 8192, W1T, 8192, PART);
    gs_mlp1_reduce<<<2048, 256, 0, stream>>>(PART, mlp1_b1, T1);
    gs_pool<<<2048, 64, 0, stream>>>(T1, mlp1_W2, mlp1_b2, pooled);

    // --- BN + MLP2 -> out[8,8] ---
    gs_bn_mlp2<<<1, 256, 0, stream>>>(pooled, bn_gamma, bn_beta, mlp2_W1, mlp2_b1,
                                      mlp2_W2, mlp2_b2, out);
}